// Round 8
// baseline (40056.982 us; speedup 1.0000x reference)
//
#include <hip/hip_runtime.h>
#include <stdint.h>

// DSNN bit-exact fp32. Locked-in facts:
//  - Ref is k-ascending single-accumulator fma (R1/R4/R5/R6/R7 absmax 0.0);
//    any reorder/reprecision flips spikes chaotically (R2: 511). Dense fmaf
//    with spike in {0.0,1.0} is bitwise == conditional add. No MFMA.
//  - R4(4x4)/R7(8x2) both cap at VALUBusy 53% regardless of TCP ratio ->
//    binder is latency convoys: lockstep waves issue loads together and
//    stall together; no cross-iteration overlap.
//  - R8 changes: (1) rotate W load one j ahead (prefetch covers ~200cyc
//    with the fma block x 4-wave interleave); (2) ping-pong spike buffers
//    -> 2 barriers/step instead of 4; (3) h0 in registers (thread-private),
//    freeing LDS for the second spike buffer.
//  - Unified VGPR file: 128 regs/wave at 16 waves/CU. This design ~124.

typedef __attribute__((ext_vector_type(2))) float f32x2;
typedef __attribute__((ext_vector_type(4))) float f32x4;

#define ALPHA 0.9f
#define BETA 0.85f
#define NSTEPS 127
#define WGT 1024
#define ROWS 32
#define CPAD 36     // spike-buffer col stride (floats): 32 rows + 4 pad

// Update forms verbatim from R1/R4 (bit-exact-verified vs np reference).
#define LIF_L0(M, H, SP) { float _m = BETA * (M) + (H); \
    const bool _b = (_m - 1.0f) > 0.0f; (M) = _b ? 0.0f : _m; \
    (SP) = _b ? 1.0f : 0.0f; }
#define LIF_MID(S, M, A, SP) { (S) = ALPHA * (S) + (A); \
    float _m = BETA * (M) + (S); const bool _b = (_m - 1.0f) > 0.0f; \
    (M) = _b ? 0.0f : _m; (SP) = _b ? 1.0f : 0.0f; }
#define LIF_OUT(S, M, A) { (S) = ALPHA * (S) + (A); (M) = BETA * (M) + (S); }

__global__ __launch_bounds__(WGT, 4)
void dsnn_kernel(const float* __restrict__ x,
                 const float* __restrict__ W0,
                 const float* __restrict__ W1,
                 const float* __restrict__ W2,
                 float* __restrict__ out)
{
    __shared__ float bufP[512 * CPAD];   // 73728 B: x-stage, then L0 spikes
    __shared__ float bufQ[512 * CPAD];   // 73728 B: L1 spikes

    const int t  = threadIdx.x;
    const int c2 = (t & 255) * 2;          // cols c2, c2+1
    const int g  = (t >> 8) * 8;           // rows g..g+7 (wave-uniform)
    const int r0 = blockIdx.x * ROWS;

    // ---- stage x (pos/neg split) into bufP [i][row], i = 0..255 ----
    for (int k = t; k < 256 * ROWS; k += WGT) {
        const int i = k >> 5;
        const int r = k & 31;
        const float v = (i < 128) ? x[(size_t)(r0 + r) * 128 + i]
                                  : -x[(size_t)(r0 + r) * 128 + (i - 128)];
        bufP[i * CPAD + r] = fmaxf(v, 0.0f);
    }
    __syncthreads();

    float acc[8][2];   // [row r][col cc]

    // acc[r][cc] += sbuf[j][g+r] * W[j][c2+cc], j ascending (bit-exact order).
    // W load rotated one j ahead so the global load never stalls at its use.
    auto gemm = [&](const float* Wcol, const float* sbuf, int K) {
        const float* sb = sbuf + g;
        f32x2 pw = *(const f32x2*)(Wcol);
        #pragma unroll 4
        for (int j = 0; j < K - 1; ++j) {
            const f32x2 cw = pw;
            pw = *(const f32x2*)(Wcol + (size_t)(j + 1) * 512);   // prefetch j+1
            const f32x4 sA = *(const f32x4*)(sb);                 // rows g..g+3
            const f32x4 sB = *(const f32x4*)(sb + 4);             // rows g+4..g+7
            sb += CPAD;
            #pragma unroll
            for (int rr = 0; rr < 4; ++rr) {
                acc[rr][0]     = fmaf(sA[rr], cw.x, acc[rr][0]);
                acc[rr][1]     = fmaf(sA[rr], cw.y, acc[rr][1]);
                acc[4 + rr][0] = fmaf(sB[rr], cw.x, acc[4 + rr][0]);
                acc[4 + rr][1] = fmaf(sB[rr], cw.y, acc[4 + rr][1]);
            }
        }
        {   // tail j = K-1
            const f32x4 sA = *(const f32x4*)(sb);
            const f32x4 sB = *(const f32x4*)(sb + 4);
            #pragma unroll
            for (int rr = 0; rr < 4; ++rr) {
                acc[rr][0]     = fmaf(sA[rr], pw.x, acc[rr][0]);
                acc[rr][1]     = fmaf(sA[rr], pw.y, acc[rr][1]);
                acc[4 + rr][0] = fmaf(sB[rr], pw.x, acc[4 + rr][0]);
                acc[4 + rr][1] = fmaf(sB[rr], pw.y, acc[4 + rr][1]);
            }
        }
    };

    // ---- h0 = x @ W0 (time-invariant) -> registers (thread-private) ----
    #pragma unroll
    for (int r = 0; r < 8; ++r) { acc[r][0] = 0.0f; acc[r][1] = 0.0f; }
    gemm(W0 + c2, bufP, 256);
    float h0r[8][2];
    #pragma unroll
    for (int r = 0; r < 8; ++r) { h0r[r][0] = acc[r][0]; h0r[r][1] = acc[r][1]; }
    __syncthreads();   // all x-reads done before bufP is reused for L0 spikes

    // ---- recurrent state in registers: 5 x 16 = 80 ----
    float m0[8][2], s1[8][2], m1[8][2], s2[8][2], m2[8][2];
    #pragma unroll
    for (int r = 0; r < 8; ++r)
        #pragma unroll
        for (int cc = 0; cc < 2; ++cc) {
            m0[r][cc] = 0.f; s1[r][cc] = 0.f; m1[r][cc] = 0.f;
            s2[r][cc] = 0.f; m2[r][cc] = 0.f;
        }

    for (int step = 0; step < NSTEPS; ++step) {
        // ===== layer 0: m0 = BETA*m0 + h0; spike; reset; spikes -> bufP =====
        {
            f32x4 svA[2], svB[2];   // [cc] rows g..g+3 / g+4..g+7
            #pragma unroll
            for (int rr = 0; rr < 4; ++rr) {
                LIF_L0(m0[rr][0], h0r[rr][0], svA[0][rr]);
                LIF_L0(m0[rr][1], h0r[rr][1], svA[1][rr]);
                LIF_L0(m0[4 + rr][0], h0r[4 + rr][0], svB[0][rr]);
                LIF_L0(m0[4 + rr][1], h0r[4 + rr][1], svB[1][rr]);
            }
            #pragma unroll
            for (int cc = 0; cc < 2; ++cc) {
                *(f32x4*)(bufP + (c2 + cc) * CPAD + g)     = svA[cc];
                *(f32x4*)(bufP + (c2 + cc) * CPAD + g + 4) = svB[cc];
            }
        }
        __syncthreads();   // A: L0 spikes visible; also retires gemm2(s-1) bufQ reads

        // ===== layer 1: h1 = spk0 @ W1 (reads bufP) =====
        #pragma unroll
        for (int r = 0; r < 8; ++r) { acc[r][0] = 0.0f; acc[r][1] = 0.0f; }
        gemm(W1 + c2, bufP, 512);

        {
            f32x4 svA[2], svB[2];
            #pragma unroll
            for (int rr = 0; rr < 4; ++rr) {
                LIF_MID(s1[rr][0], m1[rr][0], acc[rr][0], svA[0][rr]);
                LIF_MID(s1[rr][1], m1[rr][1], acc[rr][1], svA[1][rr]);
                LIF_MID(s1[4 + rr][0], m1[4 + rr][0], acc[4 + rr][0], svB[0][rr]);
                LIF_MID(s1[4 + rr][1], m1[4 + rr][1], acc[4 + rr][1], svB[1][rr]);
            }
            #pragma unroll
            for (int cc = 0; cc < 2; ++cc) {
                *(f32x4*)(bufQ + (c2 + cc) * CPAD + g)     = svA[cc];
                *(f32x4*)(bufQ + (c2 + cc) * CPAD + g + 4) = svB[cc];
            }
        }
        __syncthreads();   // C: L1 spikes visible; also retires gemm1 bufP reads

        // ===== layer 2: h2 = spk1 @ W2 (reads bufQ); s2,m2 update =====
        #pragma unroll
        for (int r = 0; r < 8; ++r) { acc[r][0] = 0.0f; acc[r][1] = 0.0f; }
        gemm(W2 + c2, bufQ, 512);
        #pragma unroll
        for (int r = 0; r < 8; ++r) {
            LIF_OUT(s2[r][0], m2[r][0], acc[r][0]);
            LIF_OUT(s2[r][1], m2[r][1], acc[r][1]);
        }
        // no barrier: next L0 writes bufP (retired by C); next LIF_MID writes
        // bufQ only after next A (which retires this gemm2's bufQ reads).
    }

    // ---- write final m2 ----
    #pragma unroll
    for (int r = 0; r < 8; ++r) {
        f32x2 ov = { m2[r][0], m2[r][1] };
        *(f32x2*)(out + (size_t)(r0 + g + r) * 512 + c2) = ov;
    }
}

extern "C" void kernel_launch(void* const* d_in, const int* in_sizes, int n_in,
                              void* d_out, int out_size, void* d_ws, size_t ws_size,
                              hipStream_t stream) {
    const float* inputs = (const float*)d_in[0];   // 16384 x 128
    const float* W0     = (const float*)d_in[1];   // 256 x 512
    const float* W1     = (const float*)d_in[2];   // 512 x 512
    const float* W2     = (const float*)d_in[3];   // 512 x 512
    float* out          = (float*)d_out;           // 16384 x 512

    dim3 grid(16384 / ROWS);     // 512 workgroups, 32 rows each
    dim3 block(WGT);
    dsnn_kernel<<<grid, block, 0, stream>>>(inputs, W0, W1, W2, out);
}

// Round 9
// 36329.306 us; speedup vs baseline: 1.1026x; 1.1026x over previous
//
#include <hip/hip_runtime.h>
#include <stdint.h>

// DSNN bit-exact fp32. Locked-in facts:
//  - Ref = k-ascending single-accumulator fma (R1/R4-R7 absmax 0.0); any
//    reorder/reprecision flips spikes chaotically (R2: 511). Dense fmaf with
//    spike in {0.0,1.0} is bitwise == conditional add. No MFMA.
//  - Pipe model per CU-j (tile RxC, RC=16): VALU 128, TCP(W)=64C, LDS(spk)=16R
//    -> R7 (8,2) = 128/128/128, three saturated pipes, 53% cap. Fix = remove
//    TCP demand: W staged to LDS (global_load_lds w16, double-buffered,
//    16 waves x 1 row/block), read as ds_read_b64.
//  - Unified reg file: 128 VGPR+AGPR per wave at 16 waves/CU. R8's h0-in-regs
//    spilled (WRITE 595 MB). Here h0 lives in d_out (private per thread,
//    L2-resident; final m2 store overwrites it). ~110 regs.

typedef __attribute__((ext_vector_type(2))) float f32x2;
typedef __attribute__((ext_vector_type(4))) float f32x4;

#define ALPHA 0.9f
#define BETA 0.85f
#define NSTEPS 127
#define WGT 1024
#define ROWS 32
#define CPAD 36     // spkbuf col stride (floats); j-stride 144 B (16B-aligned for b128)
#define BK 16       // W rows per staged block

#define GAS __attribute__((address_space(1)))
#define LAS __attribute__((address_space(3)))

// Update forms verbatim from R1/R4 (bit-exact-verified vs np reference).
#define LIF_L0(M, H, SP) { float _m = BETA * (M) + (H); \
    const bool _b = (_m - 1.0f) > 0.0f; (M) = _b ? 0.0f : _m; \
    (SP) = _b ? 1.0f : 0.0f; }
#define LIF_MID(S, M, A, SP) { (S) = ALPHA * (S) + (A); \
    float _m = BETA * (M) + (S); const bool _b = (_m - 1.0f) > 0.0f; \
    (M) = _b ? 0.0f : _m; (SP) = _b ? 1.0f : 0.0f; }
#define LIF_OUT(S, M, A) { (S) = ALPHA * (S) + (A); (M) = BETA * (M) + (S); }

__global__ __launch_bounds__(WGT, 4)
void dsnn_kernel(const float* __restrict__ x,
                 const float* __restrict__ W0,
                 const float* __restrict__ W1,
                 const float* __restrict__ W2,
                 float* __restrict__ out)
{
    __shared__ float spkbuf[512 * CPAD];      // 73728 B: x-stage, then spikes
    __shared__ float Wb[2][BK * 512];         // 2 x 32768 B: staged W blocks

    const int t    = threadIdx.x;
    const int lane = t & 63;
    const int w    = t >> 6;                  // wave id 0..15
    const int c2   = (t & 255) * 2;           // cols c2, c2+1
    const int g    = (t >> 8) * 8;            // rows g..g+7 (wave-uniform)
    const int r0   = blockIdx.x * ROWS;

    // ---- stage x (pos/neg split) into spkbuf [i][row], i = 0..255 ----
    for (int k = t; k < 256 * ROWS; k += WGT) {
        const int i = k >> 5;
        const int r = k & 31;
        const float v = (i < 128) ? x[(size_t)(r0 + r) * 128 + i]
                                  : -x[(size_t)(r0 + r) * 128 + (i - 128)];
        spkbuf[i * CPAD + r] = fmaxf(v, 0.0f);
    }

    // Stage W rows [jbase, jbase+16) into Wb[buf]; wave w stages row jbase+w.
    auto stage = [&](const float* Wsrc, int jbase, int buf) {
        const float* gp = Wsrc + (size_t)(jbase + w) * 512 + lane * 4;
        float* lp = &Wb[buf][w * 512 + lane * 4];
        __builtin_amdgcn_global_load_lds((const GAS void*)gp,        (LAS void*)lp,        16, 0, 0);
        __builtin_amdgcn_global_load_lds((const GAS void*)(gp+256),  (LAS void*)(lp+256),  16, 0, 0);
    };

    float acc[8][2];   // [row r][col cc]

    // One 16-j block: acc += spk[j][g+r] * Wlds[jl][c2+cc], j ascending.
    auto compute16 = [&](const float* wb, const float* sb) {
        #pragma unroll
        for (int jl = 0; jl < BK; ++jl) {
            const f32x4 sA = *(const f32x4*)(sb + jl * CPAD);       // rows g..g+3
            const f32x4 sB = *(const f32x4*)(sb + jl * CPAD + 4);   // rows g+4..g+7
            const f32x2 wv = *(const f32x2*)(wb + jl * 512);
            #pragma unroll
            for (int rr = 0; rr < 4; ++rr) {
                acc[rr][0]     = fmaf(sA[rr], wv.x, acc[rr][0]);
                acc[rr][1]     = fmaf(sA[rr], wv.y, acc[rr][1]);
                acc[4 + rr][0] = fmaf(sB[rr], wv.x, acc[4 + rr][0]);
                acc[4 + rr][1] = fmaf(sB[rr], wv.y, acc[4 + rr][1]);
            }
        }
    };

    // Full gemm over K rows of Wsrc (K % 16 == 0), double-buffered staging.
    auto gemm = [&](const float* Wsrc, int K) {
        const int NB = K / BK;
        stage(Wsrc, 0, 0);
        __syncthreads();                        // staging of block 0 complete
        for (int b = 0; b < NB; ++b) {
            if (b + 1 < NB) stage(Wsrc, (b + 1) * BK, (b + 1) & 1);
            compute16(&Wb[b & 1][c2], spkbuf + b * (BK * CPAD) + g);
            __syncthreads();                    // stage(b+1) done; reads of Wb[b&1] done
        }
    };

    // ---- h0 = x @ W0 (time-invariant) -> park in d_out (private per thread) ----
    #pragma unroll
    for (int r = 0; r < 8; ++r) { acc[r][0] = 0.0f; acc[r][1] = 0.0f; }
    gemm(W0, 256);
    #pragma unroll
    for (int r = 0; r < 8; ++r) {
        f32x2 hv = { acc[r][0], acc[r][1] };
        *(f32x2*)(out + (size_t)(r0 + g + r) * 512 + c2) = hv;
    }
    // last gemm sync already retired all spkbuf(x) reads; spkbuf reusable.

    // ---- recurrent state in registers: 5 x 16 = 80 ----
    float m0[8][2], s1[8][2], m1[8][2], s2[8][2], m2[8][2];
    #pragma unroll
    for (int r = 0; r < 8; ++r)
        #pragma unroll
        for (int cc = 0; cc < 2; ++cc) {
            m0[r][cc] = 0.f; s1[r][cc] = 0.f; m1[r][cc] = 0.f;
            s2[r][cc] = 0.f; m2[r][cc] = 0.f;
        }

    for (int step = 0; step < NSTEPS; ++step) {
        // ===== layer 0: m0 = BETA*m0 + h0; spike; reset; spikes -> spkbuf =====
        {
            f32x4 svA[2], svB[2];   // [cc] rows g..g+3 / g+4..g+7
            #pragma unroll
            for (int rr = 0; rr < 4; ++rr) {
                const f32x2 hva = *(const f32x2*)(out + (size_t)(r0 + g + rr) * 512 + c2);
                const f32x2 hvb = *(const f32x2*)(out + (size_t)(r0 + g + 4 + rr) * 512 + c2);
                LIF_L0(m0[rr][0], hva.x, svA[0][rr]);
                LIF_L0(m0[rr][1], hva.y, svA[1][rr]);
                LIF_L0(m0[4 + rr][0], hvb.x, svB[0][rr]);
                LIF_L0(m0[4 + rr][1], hvb.y, svB[1][rr]);
            }
            #pragma unroll
            for (int cc = 0; cc < 2; ++cc) {
                *(f32x4*)(spkbuf + (c2 + cc) * CPAD + g)     = svA[cc];
                *(f32x4*)(spkbuf + (c2 + cc) * CPAD + g + 4) = svB[cc];
            }
        }
        __syncthreads();   // A: L0 spikes visible (gemm2(s-1) reads retired by its last sync)

        // ===== layer 1: h1 = spk0 @ W1 =====
        #pragma unroll
        for (int r = 0; r < 8; ++r) { acc[r][0] = 0.0f; acc[r][1] = 0.0f; }
        gemm(W1, 512);     // last sync retires all spkbuf(L0) reads

        {
            f32x4 svA[2], svB[2];
            #pragma unroll
            for (int rr = 0; rr < 4; ++rr) {
                LIF_MID(s1[rr][0], m1[rr][0], acc[rr][0], svA[0][rr]);
                LIF_MID(s1[rr][1], m1[rr][1], acc[rr][1], svA[1][rr]);
                LIF_MID(s1[4 + rr][0], m1[4 + rr][0], acc[4 + rr][0], svB[0][rr]);
                LIF_MID(s1[4 + rr][1], m1[4 + rr][1], acc[4 + rr][1], svB[1][rr]);
            }
            #pragma unroll
            for (int cc = 0; cc < 2; ++cc) {
                *(f32x4*)(spkbuf + (c2 + cc) * CPAD + g)     = svA[cc];
                *(f32x4*)(spkbuf + (c2 + cc) * CPAD + g + 4) = svB[cc];
            }
        }
        __syncthreads();   // C: L1 spikes visible

        // ===== layer 2: h2 = spk1 @ W2; s2,m2 update; no reset =====
        #pragma unroll
        for (int r = 0; r < 8; ++r) { acc[r][0] = 0.0f; acc[r][1] = 0.0f; }
        gemm(W2, 512);     // last sync retires all spkbuf(L1) reads
        #pragma unroll
        for (int r = 0; r < 8; ++r) {
            LIF_OUT(s2[r][0], m2[r][0], acc[r][0]);
            LIF_OUT(s2[r][1], m2[r][1], acc[r][1]);
        }
        // next L0 may write spkbuf immediately: gemm2's last sync retired reads.
    }

    // ---- write final m2 (overwrites the h0 parking) ----
    #pragma unroll
    for (int r = 0; r < 8; ++r) {
        f32x2 ov = { m2[r][0], m2[r][1] };
        *(f32x2*)(out + (size_t)(r0 + g + r) * 512 + c2) = ov;
    }
}

extern "C" void kernel_launch(void* const* d_in, const int* in_sizes, int n_in,
                              void* d_out, int out_size, void* d_ws, size_t ws_size,
                              hipStream_t stream) {
    const float* inputs = (const float*)d_in[0];   // 16384 x 128
    const float* W0     = (const float*)d_in[1];   // 256 x 512
    const float* W1     = (const float*)d_in[2];   // 512 x 512
    const float* W2     = (const float*)d_in[3];   // 512 x 512
    float* out          = (float*)d_out;           // 16384 x 512

    dim3 grid(16384 / ROWS);     // 512 workgroups, 32 rows each
    dim3 block(WGT);
    dsnn_kernel<<<grid, block, 0, stream>>>(inputs, W0, W1, W2, out);
}